// Round 1
// baseline (34259.668 us; speedup 1.0000x reference)
//
#include <hip/hip_runtime.h>
#include <hip/hip_bf16.h>

#define SEQ   1024
#define BATCH 64
#define INDIM 512
#define HID   1024

typedef __attribute__((ext_vector_type(8))) short bf16x8;
typedef __attribute__((ext_vector_type(4))) float f32x4;

// fp32 -> bf16 round-to-nearest-even (values are tame; no NaN handling needed)
static __device__ __forceinline__ short f2bf(float f) {
    union { float f; unsigned u; } v; v.f = f;
    unsigned u = v.u;
    unsigned r = u + 0x7fffu + ((u >> 16) & 1u);
    return (short)(r >> 16);
}

__global__ __launch_bounds__(256) void cvt_kernel(const float* __restrict__ src,
                                                  short* __restrict__ dst, int n) {
    int i = blockIdx.x * blockDim.x + threadIdx.x;
    int stride = gridDim.x * blockDim.x;
    for (; i < n; i += stride) dst[i] = f2bf(src[i]);
}

// Phase A: xp[m,n] = sum_k x[m,k]*Wih[n,k] + b_ih[n] + b_hh[n]
// m = s*BATCH+b (65536 rows), written into d_out (same layout as final output).
// 64x64 block tile, 4 waves as 2x2, each wave 2x2 MFMA tiles of 16x16x32 bf16.
__global__ __launch_bounds__(256) void proj_kernel(
    const float* __restrict__ x,      // [65536, 512] fp32
    const short* __restrict__ wih,    // [1024, 512] bf16
    const float* __restrict__ b_ih,
    const float* __restrict__ b_hh,
    float* __restrict__ out)          // [65536, 1024] fp32
{
    const int tid  = threadIdx.x;
    const int lane = tid & 63;
    const int w    = tid >> 6;
    const int wm   = w & 1, wn = w >> 1;
    const int l15  = lane & 15;
    const int quad = lane >> 4;

    const int bm = blockIdx.y * 64 + wm * 32;
    const int bn = blockIdx.x * 64 + wn * 32;

    f32x4 acc[2][2] = {};

    for (int kk = 0; kk < INDIM; kk += 32) {
        const int kbase = kk + quad * 8;
        bf16x8 a[2], b[2];
#pragma unroll
        for (int mi = 0; mi < 2; ++mi) {
            const float* ap = x + (size_t)(bm + mi * 16 + l15) * INDIM + kbase;
            float4 lo = *reinterpret_cast<const float4*>(ap);
            float4 hi = *reinterpret_cast<const float4*>(ap + 4);
            bf16x8 af;
            af[0] = f2bf(lo.x); af[1] = f2bf(lo.y); af[2] = f2bf(lo.z); af[3] = f2bf(lo.w);
            af[4] = f2bf(hi.x); af[5] = f2bf(hi.y); af[6] = f2bf(hi.z); af[7] = f2bf(hi.w);
            a[mi] = af;
        }
#pragma unroll
        for (int ni = 0; ni < 2; ++ni)
            b[ni] = *reinterpret_cast<const bf16x8*>(wih + (size_t)(bn + ni * 16 + l15) * INDIM + kbase);
#pragma unroll
        for (int mi = 0; mi < 2; ++mi)
#pragma unroll
            for (int ni = 0; ni < 2; ++ni)
                acc[mi][ni] = __builtin_amdgcn_mfma_f32_16x16x32_bf16(a[mi], b[ni], acc[mi][ni], 0, 0, 0);
    }

#pragma unroll
    for (int mi = 0; mi < 2; ++mi) {
#pragma unroll
        for (int ni = 0; ni < 2; ++ni) {
            const int col = bn + ni * 16 + l15;
            const float bias = b_ih[col] + b_hh[col];
#pragma unroll
            for (int reg = 0; reg < 4; ++reg) {
                const int row = bm + mi * 16 + quad * 4 + reg;
                out[(size_t)row * HID + col] = acc[mi][ni][reg] + bias;
            }
        }
    }
}

// Phase B: cooperative scan. 256 blocks = 4 groups x 64 blocks.
// Group g owns batches [16g,16g+16); block r in group owns cols [16r,16r+16).
// W_hh B-fragments live in VGPRs for the whole kernel (wave w covers k in [256w,256w+256)).
// h ping-pongs through global bf16 buffers; one flag-barrier per step.
__global__ __launch_bounds__(256) void rnn_scan_kernel(
    float* __restrict__ out,              // [SEQ,BATCH,HID]: holds xp, overwritten with h_t
    const short* __restrict__ whh,        // [1024,1024] bf16
    short* __restrict__ hb0,              // [BATCH,HID] bf16 (zeroed = h0)
    short* __restrict__ hb1,              // [BATCH,HID] bf16
    unsigned int* __restrict__ flags)     // [256], zeroed
{
    const int tid  = threadIdx.x;
    const int lane = tid & 63;
    const int w    = tid >> 6;
    const int l15  = lane & 15;
    const int quad = lane >> 4;

    const int gid = blockIdx.x;
    const int g   = gid >> 6;     // group 0..3
    const int r   = gid & 63;     // column block 0..63
    const int b0  = g * 16;       // first batch of group
    const int n0  = r * 16;       // first hidden col of block

    // Preload W_hh fragments into registers (loop-invariant across all 1024 steps).
    bf16x8 wfrag[8];
#pragma unroll
    for (int ks = 0; ks < 8; ++ks) {
        const int k = 256 * w + ks * 32 + quad * 8;
        wfrag[ks] = *reinterpret_cast<const bf16x8*>(whh + (size_t)(n0 + l15) * HID + k);
    }

    __shared__ float red[4 * 256];

    short* hbufs[2] = { hb0, hb1 };

    for (int t = 0; t < SEQ; ++t) {
        const short* hc = hbufs[t & 1];
        short*       hn = hbufs[(t + 1) & 1];

        // Partial GEMM: wave w accumulates its K-quarter of the 16x16 tile.
        f32x4 acc = {0.f, 0.f, 0.f, 0.f};
#pragma unroll
        for (int ks = 0; ks < 8; ++ks) {
            const int k = 256 * w + ks * 32 + quad * 8;
            bf16x8 afrag = *reinterpret_cast<const bf16x8*>(hc + (size_t)(b0 + l15) * HID + k);
            acc = __builtin_amdgcn_mfma_f32_16x16x32_bf16(afrag, wfrag[ks], acc, 0, 0, 0);
        }

        // Cross-wave K-reduction through LDS. C/D layout: col=lane&15, row=quad*4+reg.
#pragma unroll
        for (int reg = 0; reg < 4; ++reg) {
            const int e = l15 + 16 * (quad * 4 + reg);   // col + 16*row
            red[w * 256 + e] = acc[reg];
        }
        __syncthreads();

        {
            const int m = tid >> 4;   // batch within group (row)
            const int n = tid & 15;   // col within tile
            const int b = b0 + m;
            const int j = n0 + n;
            const float s = red[0 * 256 + tid] + red[1 * 256 + tid] +
                            red[2 * 256 + tid] + red[3 * 256 + tid];
            const size_t oidx = (size_t)t * (BATCH * HID) + (size_t)b * HID + j;
            const float v = tanhf(s + out[oidx]);   // xp read, h written in place
            out[oidx] = v;
            hn[b * HID + j] = f2bf(v);
        }

        // Group barrier: publish our slice, wait for the other 63 blocks.
        __threadfence();
        __syncthreads();
        if (tid == 0)
            __hip_atomic_store(&flags[gid], (unsigned)(t + 1),
                               __ATOMIC_RELEASE, __HIP_MEMORY_SCOPE_AGENT);
        if (tid < 64) {
            while (__hip_atomic_load(&flags[g * 64 + tid],
                                     __ATOMIC_ACQUIRE, __HIP_MEMORY_SCOPE_AGENT)
                   < (unsigned)(t + 1)) { }
        }
        __syncthreads();
    }
}

extern "C" void kernel_launch(void* const* d_in, const int* in_sizes, int n_in,
                              void* d_out, int out_size, void* d_ws, size_t ws_size,
                              hipStream_t stream) {
    const float* x    = (const float*)d_in[0];   // [1024,64,512]
    const float* wih  = (const float*)d_in[1];   // [1024,512]
    const float* whh  = (const float*)d_in[2];   // [1024,1024]
    const float* b_ih = (const float*)d_in[3];   // [1024]
    const float* b_hh = (const float*)d_in[4];   // [1024]
    float* out = (float*)d_out;                  // [1024,64,1024]

    char* ws = (char*)d_ws;
    // ws layout (all 16B-aligned):
    unsigned int* flags = (unsigned int*)(ws + 0);            // 1 KB
    short* hb0    = (short*)(ws + 4096);                      // 128 KB
    short* hb1    = (short*)(ws + 4096 + 131072);             // 128 KB
    short* wih_bf = (short*)(ws + 266240);                    // 1 MB
    short* whh_bf = (short*)(ws + 1314816);                   // 2 MB  (total ~3.3 MB)

    // Zero flags + h0 (+hb1). ws is re-poisoned to 0xAA before every timed call.
    hipMemsetAsync(d_ws, 0, 266240, stream);

    cvt_kernel<<<512, 256, 0, stream>>>(wih, wih_bf, HID * INDIM);
    cvt_kernel<<<1024, 256, 0, stream>>>(whh, whh_bf, HID * HID);

    dim3 pgrid(HID / 64, (SEQ * BATCH) / 64);   // (16, 1024)
    proj_kernel<<<pgrid, 256, 0, stream>>>(x, wih_bf, b_ih, b_hh, out);

    void* args[] = { (void*)&out, (void*)&whh_bf, (void*)&hb0, (void*)&hb1, (void*)&flags };
    hipLaunchCooperativeKernel((const void*)rnn_scan_kernel, dim3(256), dim3(256),
                               args, 0, stream);
}

// Round 3
// 5853.135 us; speedup vs baseline: 5.8532x; 5.8532x over previous
//
#include <hip/hip_runtime.h>
#include <hip/hip_bf16.h>

#define SEQ   1024
#define BATCH 64
#define INDIM 512
#define HID   1024

typedef __attribute__((ext_vector_type(8))) short bf16x8;
typedef __attribute__((ext_vector_type(4))) float f32x4;
typedef __attribute__((ext_vector_type(4))) int   i32x4;

// fp32 -> bf16 round-to-nearest-even
static __device__ __forceinline__ short f2bf(float f) {
    union { float f; unsigned u; } v; v.f = f;
    unsigned u = v.u;
    unsigned r = u + 0x7fffu + ((u >> 16) & 1u);
    return (short)(r >> 16);
}

// 16B device-coherent load: bypass L1 + XCD L2, read at the MALL coherence point.
static __device__ __forceinline__ i32x4 load16_coherent(const void* p) {
    i32x4 r;
    asm volatile("global_load_dwordx4 %0, %1, off sc0 sc1" : "=v"(r) : "v"(p) : "memory");
    return r;
}

__global__ __launch_bounds__(256) void cvt_kernel(const float* __restrict__ src,
                                                  short* __restrict__ dst, int n) {
    int i = blockIdx.x * blockDim.x + threadIdx.x;
    int stride = gridDim.x * blockDim.x;
    for (; i < n; i += stride) dst[i] = f2bf(src[i]);
}

// Phase A: xp[m,n] = sum_k x[m,k]*Wih[n,k] + b_ih[n] + b_hh[n], written into d_out.
__global__ __launch_bounds__(256) void proj_kernel(
    const float* __restrict__ x,      // [65536, 512] fp32
    const short* __restrict__ wih,    // [1024, 512] bf16
    const float* __restrict__ b_ih,
    const float* __restrict__ b_hh,
    float* __restrict__ out)          // [65536, 1024] fp32
{
    const int tid  = threadIdx.x;
    const int lane = tid & 63;
    const int w    = tid >> 6;
    const int wm   = w & 1, wn = w >> 1;
    const int l15  = lane & 15;
    const int quad = lane >> 4;

    const int bm = blockIdx.y * 64 + wm * 32;
    const int bn = blockIdx.x * 64 + wn * 32;

    f32x4 acc[2][2] = {};

    for (int kk = 0; kk < INDIM; kk += 32) {
        const int kbase = kk + quad * 8;
        bf16x8 a[2], b[2];
#pragma unroll
        for (int mi = 0; mi < 2; ++mi) {
            const float* ap = x + (size_t)(bm + mi * 16 + l15) * INDIM + kbase;
            float4 lo = *reinterpret_cast<const float4*>(ap);
            float4 hi = *reinterpret_cast<const float4*>(ap + 4);
            bf16x8 af;
            af[0] = f2bf(lo.x); af[1] = f2bf(lo.y); af[2] = f2bf(lo.z); af[3] = f2bf(lo.w);
            af[4] = f2bf(hi.x); af[5] = f2bf(hi.y); af[6] = f2bf(hi.z); af[7] = f2bf(hi.w);
            a[mi] = af;
        }
#pragma unroll
        for (int ni = 0; ni < 2; ++ni)
            b[ni] = *reinterpret_cast<const bf16x8*>(wih + (size_t)(bn + ni * 16 + l15) * INDIM + kbase);
#pragma unroll
        for (int mi = 0; mi < 2; ++mi)
#pragma unroll
            for (int ni = 0; ni < 2; ++ni)
                acc[mi][ni] = __builtin_amdgcn_mfma_f32_16x16x32_bf16(a[mi], b[ni], acc[mi][ni], 0, 0, 0);
    }

#pragma unroll
    for (int mi = 0; mi < 2; ++mi) {
#pragma unroll
        for (int ni = 0; ni < 2; ++ni) {
            const int col = bn + ni * 16 + l15;
            const float bias = b_ih[col] + b_hh[col];
#pragma unroll
            for (int reg = 0; reg < 4; ++reg) {
                const int row = bm + mi * 16 + quad * 4 + reg;
                out[(size_t)row * HID + col] = acc[mi][ni][reg] + bias;
            }
        }
    }
}

// Phase B: cooperative scan. 64 blocks = 4 groups x 16 blocks.
// Group g owns batches [16g,16g+16); block r in group owns cols [64r,64r+64).
// W_hh slice (64 cols x 1024 k, bf16) lives in 128 VGPRs/thread for the whole kernel.
// Barrier per step: sc1 h stores -> __syncthreads (per-thread vmcnt0: stores >= L2)
// -> tid0 fence(release,agent) (buffer_wbl2 sc1: L2 write queue -> MALL) -> counter
// add -> relaxed poll -> fence(acquire,agent) -> __syncthreads -> sc1 h loads.
__global__ __launch_bounds__(256) void rnn_scan_kernel(
    float* __restrict__ out,              // [SEQ,BATCH,HID]: holds xp, overwritten with h_t
    const short* __restrict__ whh,        // [1024,1024] bf16
    short* __restrict__ hb0,              // [BATCH,HID] bf16 (zeroed = h0)
    short* __restrict__ hb1,              // [BATCH,HID] bf16
    unsigned int* __restrict__ ctr)       // 4 counters, 256B apart, zeroed
{
    const int tid  = threadIdx.x;
    const int lane = tid & 63;
    const int w    = tid >> 6;
    const int l15  = lane & 15;
    const int quad = lane >> 4;

    const int gid = blockIdx.x;   // 0..63
    const int g   = gid >> 4;     // group 0..3
    const int r   = gid & 15;     // col-block 0..15
    const int b0  = g * 16;       // first batch of group
    const int n0  = r * 64;       // first hidden col of block

    // Preload W_hh fragments (loop-invariant): n-tile nt covers cols n0+16nt+l15,
    // wave w covers k in [256w, 256w+256).
    bf16x8 wfrag[4][8];
#pragma unroll
    for (int nt = 0; nt < 4; ++nt)
#pragma unroll
        for (int ks = 0; ks < 8; ++ks) {
            const int k = 256 * w + ks * 32 + quad * 8;
            wfrag[nt][ks] = *reinterpret_cast<const bf16x8*>(
                whh + (size_t)(n0 + nt * 16 + l15) * HID + k);
        }

    __shared__ float red[4 * 1024];

    short* hbufs[2] = { hb0, hb1 };
    unsigned int* my_ctr = ctr + g * 64;   // 256B apart per group

    const int m  = tid >> 4;        // batch row within group
    const int c0 = (tid & 15) * 4;  // 4 consecutive cols per thread in epilogue

    for (int t = 0; t < SEQ; ++t) {
        const short* hc = hbufs[t & 1];
        short*       hn = hbufs[(t + 1) & 1];

        // Block-local xp prefetch (independent of the barrier) — overlaps h RT.
        const size_t oidx = (size_t)t * (BATCH * HID) + (size_t)(b0 + m) * HID + n0 + c0;
        float4 xp = *reinterpret_cast<const float4*>(out + oidx);

        // Coherent h loads: row b0+l15, wave-w K-quarter (8 x 16B, pipelined).
        i32x4 araw[8];
        const short* abase = hc + (size_t)(b0 + l15) * HID + 256 * w + quad * 8;
#pragma unroll
        for (int ks = 0; ks < 8; ++ks)
            araw[ks] = load16_coherent(abase + ks * 32);
        // Single wait for all 8; "+v" ties create the data dependence the
        // compiler can't see through the asm loads.
        asm volatile("s_waitcnt vmcnt(0)"
            : "+v"(araw[0]), "+v"(araw[1]), "+v"(araw[2]), "+v"(araw[3]),
              "+v"(araw[4]), "+v"(araw[5]), "+v"(araw[6]), "+v"(araw[7]) :: "memory");

        f32x4 acc[4] = {};
#pragma unroll
        for (int ks = 0; ks < 8; ++ks) {
            bf16x8 a = __builtin_bit_cast(bf16x8, araw[ks]);
#pragma unroll
            for (int nt = 0; nt < 4; ++nt)
                acc[nt] = __builtin_amdgcn_mfma_f32_16x16x32_bf16(a, wfrag[nt][ks], acc[nt], 0, 0, 0);
        }

        // Cross-wave K-reduction via LDS. C/D layout: col=l15, row=quad*4+reg.
#pragma unroll
        for (int nt = 0; nt < 4; ++nt)
#pragma unroll
            for (int reg = 0; reg < 4; ++reg)
                red[w * 1024 + (quad * 4 + reg) * 64 + nt * 16 + l15] = acc[nt][reg];
        __syncthreads();

        {
            float s[4];
#pragma unroll
            for (int i = 0; i < 4; ++i)
                s[i] = red[0 * 1024 + m * 64 + c0 + i] + red[1 * 1024 + m * 64 + c0 + i] +
                       red[2 * 1024 + m * 64 + c0 + i] + red[3 * 1024 + m * 64 + c0 + i];

            float v0 = tanhf(s[0] + xp.x);
            float v1 = tanhf(s[1] + xp.y);
            float v2 = tanhf(s[2] + xp.z);
            float v3 = tanhf(s[3] + xp.w);
            *reinterpret_cast<float4*>(out + oidx) = make_float4(v0, v1, v2, v3);

            // Device-scope h store: 4 bf16 packed into one 8B relaxed atomic (sc1).
            unsigned lo = (unsigned)(unsigned short)f2bf(v0) | ((unsigned)(unsigned short)f2bf(v1) << 16);
            unsigned hi = (unsigned)(unsigned short)f2bf(v2) | ((unsigned)(unsigned short)f2bf(v3) << 16);
            unsigned long long pk = (unsigned long long)lo | ((unsigned long long)hi << 32);
            __hip_atomic_store(
                reinterpret_cast<unsigned long long*>(hn + (size_t)(b0 + m) * HID + n0 + c0),
                pk, __ATOMIC_RELAXED, __HIP_MEMORY_SCOPE_AGENT);
        }

        // __syncthreads drains every thread's stores to (at least) the L2 port.
        __syncthreads();
        if (tid == 0) {
            // Release: buffer_wbl2 sc1 drains the XCD L2 write path to the MALL,
            // closing the store->counter visibility race across MALL slices.
            __builtin_amdgcn_fence(__ATOMIC_RELEASE, "agent");
            __hip_atomic_fetch_add(my_ctr, 1u, __ATOMIC_RELAXED, __HIP_MEMORY_SCOPE_AGENT);
            const unsigned target = 16u * (unsigned)(t + 1);
            while (__hip_atomic_load(my_ctr, __ATOMIC_RELAXED, __HIP_MEMORY_SCOPE_AGENT) < target)
                __builtin_amdgcn_s_sleep(1);
            // Acquire: buffer_inv sc1 — cheap here (xp is streaming, W_hh in VGPRs).
            __builtin_amdgcn_fence(__ATOMIC_ACQUIRE, "agent");
        }
        __syncthreads();
    }
}

extern "C" void kernel_launch(void* const* d_in, const int* in_sizes, int n_in,
                              void* d_out, int out_size, void* d_ws, size_t ws_size,
                              hipStream_t stream) {
    const float* x    = (const float*)d_in[0];   // [1024,64,512]
    const float* wih  = (const float*)d_in[1];   // [1024,512]
    const float* whh  = (const float*)d_in[2];   // [1024,1024]
    const float* b_ih = (const float*)d_in[3];   // [1024]
    const float* b_hh = (const float*)d_in[4];   // [1024]
    float* out = (float*)d_out;                  // [1024,64,1024]

    char* ws = (char*)d_ws;
    unsigned int* ctr   = (unsigned int*)(ws + 0);            // 4 counters @ 256B stride
    short* hb0    = (short*)(ws + 4096);                      // 128 KB
    short* hb1    = (short*)(ws + 4096 + 131072);             // 128 KB
    short* wih_bf = (short*)(ws + 266240);                    // 1 MB
    short* whh_bf = (short*)(ws + 1314816);                   // 2 MB

    // Zero counters + h0 buffers (ws is re-poisoned to 0xAA before every timed call).
    hipMemsetAsync(d_ws, 0, 266240, stream);

    cvt_kernel<<<512, 256, 0, stream>>>(wih, wih_bf, HID * INDIM);
    cvt_kernel<<<1024, 256, 0, stream>>>(whh, whh_bf, HID * HID);

    dim3 pgrid(HID / 64, (SEQ * BATCH) / 64);   // (16, 1024)
    proj_kernel<<<pgrid, 256, 0, stream>>>(x, wih_bf, b_ih, b_hh, out);

    void* args[] = { (void*)&out, (void*)&whh_bf, (void*)&hb0, (void*)&hb1, (void*)&ctr };
    hipLaunchCooperativeKernel((const void*)rnn_scan_kernel, dim3(64), dim3(256),
                               args, 0, stream);
}